// Round 6
// baseline (768.630 us; speedup 1.0000x reference)
//
#include <hip/hip_runtime.h>
#include <stdint.h>

// Problem constants
#define B_      64
#define N_TOK   577
#define C_      768
#define H_      12
#define BH_     768      // B_*H_
#define M_ROWS  36928    // B_*N_TOK
#define M_PAD   36992    // 289 * 128
#define KEEP    289      // kept keys incl CLS
#define KP      320      // padded key count (20 * 16)

typedef __attribute__((ext_vector_type(8))) short   bf16x8;
typedef __attribute__((ext_vector_type(4))) float   floatx4;
typedef __attribute__((ext_vector_type(4))) short   short4v;

static __device__ __forceinline__ unsigned short f2bf(float f) {
  union { float f; unsigned u; } a; a.f = f;
  unsigned u = a.u;
  u = u + 0x7FFFu + ((u >> 16) & 1u);   // RNE; finite inputs
  return (unsigned short)(u >> 16);
}

static __device__ __forceinline__ void gl_lds16(const void* g, void* l) {
  __builtin_amdgcn_global_load_lds(
      (const __attribute__((address_space(1))) void*)g,
      (__attribute__((address_space(3))) void*)l, 16, 0, 0);
}

// ---------------------------------------------------------------------------
// 1. top-k(288) per (b,h) row of mask[768][576] -> pos[768][577]
__global__ void topk_kernel(const float* __restrict__ mask, int* __restrict__ pos) {
  __shared__ float vals[576];
  __shared__ int woff[9];
  int row = blockIdx.x;
  int t = threadIdx.x;
  float v = mask[(size_t)row * 576 + t];
  vals[t] = v;
  __syncthreads();
  int rank = 0;
  for (int j = 0; j < 576; ++j) {
    float u = vals[j];
    rank += ((u > v) || (u == v && j < t)) ? 1 : 0;
  }
  bool sel = rank < (KEEP - 1);
  unsigned long long ball = __ballot(sel ? 1 : 0);
  int lane = t & 63, w = t >> 6;
  int lp = __popcll(ball & ((1ull << lane) - 1ull));
  if (lane == 0) woff[w] = __popcll(ball);
  __syncthreads();
  int base = 0;
  for (int i = 0; i < w; ++i) base += woff[i];
  pos[(size_t)row * 577 + 1 + t] = sel ? (1 + base + lp) : -1;
  if (t == 0) pos[(size_t)row * 577] = 0;
}

// ---------------------------------------------------------------------------
// 2. x fp32 -> bf16, padded rows zeroed
__global__ void convx_kernel(const float* __restrict__ x, unsigned short* __restrict__ xb) {
  size_t i = ((size_t)blockIdx.x * 256 + threadIdx.x) * 4;
  short4v o;
  if (i < (size_t)M_ROWS * C_) {
    float4 v = *(const float4*)(x + i);
    o.x = (short)f2bf(v.x); o.y = (short)f2bf(v.y);
    o.z = (short)f2bf(v.z); o.w = (short)f2bf(v.w);
  } else {
    o.x = 0; o.y = 0; o.z = 0; o.w = 0;
  }
  *(short4v*)(xb + i) = o;
}

// 3. W [768][N] fp32 -> Wt [N][768] bf16, tiled 64x64 via LDS (both sides coalesced)
__global__ void convwT_kernel(const float* __restrict__ W, unsigned short* __restrict__ Wt,
                              int N) {
  __shared__ unsigned short tile[64 * 72];
  int n0 = blockIdx.x * 64, k0 = blockIdx.y * 64;
  int t = threadIdx.x;
  for (int p = 0; p < 4; ++p) {           // 64 k-rows x 16 float4 chunks
    int s = p * 256 + t;
    int k = s >> 4, nc = s & 15;
    float4 v = *(const float4*)(W + (size_t)(k0 + k) * N + n0 + nc * 4);
    short4v o;
    o.x = (short)f2bf(v.x); o.y = (short)f2bf(v.y);
    o.z = (short)f2bf(v.z); o.w = (short)f2bf(v.w);
    *(short4v*)(tile + k * 72 + nc * 4) = o;
  }
  __syncthreads();
  for (int p = 0; p < 2; ++p) {           // 64 n-rows x 8 k-chunks of 8
    int s = p * 256 + t;
    int n = s >> 3, kc = s & 7;
    bf16x8 o;
    for (int j = 0; j < 8; ++j) o[j] = (short)tile[(kc * 8 + j) * 72 + n];
    *(bf16x8*)(Wt + (size_t)(n0 + n) * 768 + k0 + kc * 8) = o;
  }
}

// 4. zero pad rows [289..320) of Kp and Vp
__global__ void zeropad_kernel(unsigned short* __restrict__ Kp, unsigned short* __restrict__ Vp) {
  size_t idx = (size_t)blockIdx.x * 256 + threadIdx.x;  // 768*31*64 exact
  int bh = (int)(idx / (31 * 64));
  int rem = (int)(idx % (31 * 64));
  int r = KEEP + rem / 64, d = rem & 63;
  size_t o = ((size_t)bh * KP + r) * 64 + d;
  Kp[o] = 0; Vp[o] = 0;
}

// ---------------------------------------------------------------------------
// 8-phase counted-vmcnt GEMM core (T3+T4+T5), 128x128 tile, BK=64, 4 waves.
// (verified in round 4)
static __device__ __forceinline__ void stage_half(const unsigned short* src,
                                                  unsigned short* lds, int tid) {
#pragma unroll
  for (int c = 0; c < 2; ++c) {
    int s = c * 256 + tid;
    int r = s >> 3, cs = s & 7;
    int gc = (cs ^ (r & 7)) << 3;
    gl_lds16(src + (size_t)r * 768 + gc, lds + s * 8);
  }
}

static __device__ __forceinline__ void gemm8_core(
    const unsigned short* __restrict__ A, const unsigned short* __restrict__ Bt,
    int m0, int n0, int tid, unsigned short* As, unsigned short* Bs,
    floatx4 (&acc)[4][4]) {
  const int lane = tid & 63, wv = tid >> 6;
  const int quad = lane >> 4, lcol = lane & 15;
  const int wm = wv & 1, wn = wv >> 1;
  const int swz = lcol & 7;

#define STG_A(kt, half) stage_half(A  + (size_t)(m0 + 64*(half)) * 768 + (kt)*64, \
                                   As + ((kt)&1)*8192 + (half)*4096, tid)
#define STG_B(kt, half) stage_half(Bt + (size_t)(n0 + 64*(half)) * 768 + (kt)*64, \
                                   Bs + ((kt)&1)*8192 + (half)*4096, tid)

  // prologue: tile0 fully, tile1 all but B-half1 (14 loads in flight/wave)
  STG_A(0, 0); STG_A(0, 1); STG_B(0, 0); STG_B(0, 1);
  STG_A(1, 0); STG_A(1, 1); STG_B(1, 0);
  asm volatile("s_waitcnt vmcnt(6)" ::: "memory");
  __builtin_amdgcn_s_barrier();

  for (int t = 0; t < 12; ++t) {
    const unsigned short* Asl = As + (t & 1) * 8192;
    const unsigned short* Bsl = Bs + (t & 1) * 8192;

    bf16x8 af[4][2], bfr[4][2];
#pragma unroll
    for (int i = 0; i < 4; ++i)
#pragma unroll
      for (int ks = 0; ks < 2; ++ks) {
        int cc = ks * 4 + quad;
        af[i][ks]  = *(const bf16x8*)(Asl + (wm * 64 + i * 16 + lcol) * 64 + ((cc ^ swz) << 3));
        bfr[i][ks] = *(const bf16x8*)(Bsl + (wn * 64 + i * 16 + lcol) * 64 + ((cc ^ swz) << 3));
      }
    if (t + 1 < 12) STG_B(t + 1, 1);
    asm volatile("s_waitcnt lgkmcnt(0)" ::: "memory");
    __builtin_amdgcn_sched_barrier(0);
    __builtin_amdgcn_s_barrier();
    __builtin_amdgcn_s_setprio(1);
#pragma unroll
    for (int j = 0; j < 4; ++j)
#pragma unroll
      for (int ks = 0; ks < 2; ++ks)
        acc[0][j] = __builtin_amdgcn_mfma_f32_16x16x32_bf16(af[0][ks], bfr[j][ks], acc[0][j], 0, 0, 0);
    __builtin_amdgcn_s_setprio(0);
    __builtin_amdgcn_s_barrier();

#pragma unroll
    for (int p = 1; p < 4; ++p) {
      if (t + 2 < 12) {
        if (p == 1)      STG_A(t + 2, 0);
        else if (p == 2) STG_A(t + 2, 1);
        else             STG_B(t + 2, 0);
      }
      __builtin_amdgcn_s_barrier();
      __builtin_amdgcn_s_setprio(1);
#pragma unroll
      for (int j = 0; j < 4; ++j)
#pragma unroll
        for (int ks = 0; ks < 2; ++ks)
          acc[p][j] = __builtin_amdgcn_mfma_f32_16x16x32_bf16(af[p][ks], bfr[j][ks], acc[p][j], 0, 0, 0);
      __builtin_amdgcn_s_setprio(0);
      if (p == 3) {
        if (t < 10)       asm volatile("s_waitcnt vmcnt(6)" ::: "memory");
        else if (t == 10) asm volatile("s_waitcnt vmcnt(0)" ::: "memory");
      }
      __builtin_amdgcn_s_barrier();
    }
  }
#undef STG_A
#undef STG_B
}

// ---------------------------------------------------------------------------
// 5. QKV GEMM: A[M_PAD][768] x WqkvT[2304][768] -> scatter Q/Kp/Vp bf16.
//    8-phase core + XCD supertile swizzle. Kp/Vp linear layout.
__global__ __launch_bounds__(256) void qkv_gemm_kernel(
    const unsigned short* __restrict__ A, const unsigned short* __restrict__ Bt,
    const float* __restrict__ bias, const int* __restrict__ pos,
    unsigned short* __restrict__ Q, unsigned short* __restrict__ Kp,
    unsigned short* __restrict__ Vp) {
  __shared__ unsigned short As[2 * 8192];
  __shared__ unsigned short Bs[2 * 8192];
  const int tid = threadIdx.x;
  const int lane = tid & 63, wv = tid >> 6;
  const int quad = lane >> 4, lcol = lane & 15;
  const int wm = wv & 1, wn = wv >> 1;
  int sid = blockIdx.x;
  int m_t, n_t;
  if (sid < 5184) {
    int sb = sid / 48, r = sid % 48;
    int gm = sb % 36, gn = sb / 36;
    m_t = gm * 8 + (r & 7);
    n_t = gn * 6 + (r >> 3);
  } else { m_t = 288; n_t = sid - 5184; }
  const int m0 = m_t * 128, n0 = n_t * 128;

  floatx4 acc[4][4] = {};
  gemm8_core(A, Bt, m0, n0, tid, As, Bs, acc);

  // epilogue: which & h are wave-uniform (64-col span)
  const int nbase = n0 + wn * 64;
  const int which = nbase / 768;
  const int h = (nbase - which * 768) >> 6;
  float bv[4];
#pragma unroll
  for (int nt = 0; nt < 4; ++nt) bv[nt] = bias[nbase + nt * 16 + lcol];
#pragma unroll
  for (int mt = 0; mt < 4; ++mt) {
#pragma unroll
    for (int r = 0; r < 4; ++r) {
      int m = m0 + wm * 64 + mt * 16 + quad * 4 + r;
      if (m >= M_ROWS) continue;
      int b = m / 577, t = m - b * 577;
      int bh = b * 12 + h;
      if (which == 0) {
        size_t base = ((size_t)bh * 577 + t) * 64;
#pragma unroll
        for (int nt = 0; nt < 4; ++nt)
          Q[base + nt * 16 + lcol] = f2bf(acc[mt][nt][r] + bv[nt]);
      } else {
        int p = pos[(size_t)bh * 577 + t];
        if (p >= 0) {
          size_t base = ((size_t)bh * KP + p) * 64;
          unsigned short* dst = (which == 1) ? Kp : Vp;
#pragma unroll
          for (int nt = 0; nt < 4; ++nt)
            dst[base + nt * 16 + lcol] = f2bf(acc[mt][nt][r] + bv[nt]);
        }
      }
    }
  }
}

// 6. Vp[bh][320][64] -> VpT[bh][64][320], tiled 64x64 via LDS
__global__ void transv_kernel(const unsigned short* __restrict__ Vp,
                              unsigned short* __restrict__ VpT) {
  __shared__ unsigned short tile[64 * 72];
  int bh = blockIdx.y, p0 = blockIdx.x * 64;
  int t = threadIdx.x;
  for (int pp = 0; pp < 2; ++pp) {       // 64 p-rows x 8 d-chunks of 8
    int s = pp * 256 + t;
    int p = s >> 3, dc = s & 7;
    bf16x8 v = *(const bf16x8*)(Vp + ((size_t)bh * KP + p0 + p) * 64 + dc * 8);
    *(bf16x8*)(tile + p * 72 + dc * 8) = v;
  }
  __syncthreads();
  for (int pp = 0; pp < 2; ++pp) {       // 64 d-rows x 8 p-chunks of 8
    int s = pp * 256 + t;
    int d = s >> 3, pc = s & 7;
    bf16x8 o;
    for (int j = 0; j < 8; ++j) o[j] = (short)tile[(pc * 8 + j) * 72 + d];
    *(bf16x8*)(VpT + ((size_t)bh * 64 + d) * KP + p0 + pc * 8) = o;
  }
}

// ---------------------------------------------------------------------------
// 7. Attention, barrier-free (all sub-layouts verified in rounds 0/2):
//    - XCD-affine head grid: K/V of a head are L2-resident.
//    - QK^T reads K per-wave from global (round-0 pattern).
//    - softmax: 16-lane shfl reduce (round-2 code, verified).
//    - P exchanged through WAVE-PRIVATE LDS rows [w*16 .. w*16+16) with the
//      round-2 XOR swizzle — writer rows (w*16+quad*4+r) and reader rows
//      (w*16+lcol) are the same wave's, so NO __syncthreads is needed at all;
//      same-wave ds ordering is guaranteed by lgkmcnt.
//    - PV + epilogue: round-2 code verbatim.
__global__ __launch_bounds__(256) void attn_kernel(
    const unsigned short* __restrict__ Q, const unsigned short* __restrict__ Kp,
    const unsigned short* __restrict__ VpT, unsigned short* __restrict__ attnout) {
  __shared__ unsigned short P[64 * 320];   // 40960 B, wave-private 16-row slices
  const int tid = threadIdx.x;
  const int lane = tid & 63, w = tid >> 6;
  const int quad = lane >> 4, lcol = lane & 15;
  const int g = blockIdx.x;
  const int chunk = g / 80, within = g - chunk * 80;
  const int by = chunk * 8 + (within & 7);   // head index (bh)
  const int bx = within >> 3;                // q-tile 0..9
  const int q0 = bx * 64 + w * 16;

  bf16x8 aq[2];
  {
    int qr = q0 + lcol;
    if (qr < N_TOK) {
      const unsigned short* qp = Q + ((size_t)by * N_TOK + qr) * 64;
      aq[0] = *(const bf16x8*)(qp + quad * 8);
      aq[1] = *(const bf16x8*)(qp + 32 + quad * 8);
    } else {
      bf16x8 z = {0, 0, 0, 0, 0, 0, 0, 0};
      aq[0] = z; aq[1] = z;
    }
  }

  // QK^T: K streamed from global (L2-hot); nt=19 is all-padding -> skipped
  floatx4 sacc[20] = {};
  __builtin_amdgcn_s_setprio(1);
#pragma unroll
  for (int nt = 0; nt < 19; ++nt) {
    const unsigned short* kp = Kp + ((size_t)by * KP + nt * 16 + lcol) * 64;
    bf16x8 b0 = *(const bf16x8*)(kp + quad * 8);
    bf16x8 b1 = *(const bf16x8*)(kp + 32 + quad * 8);
    sacc[nt] = __builtin_amdgcn_mfma_f32_16x16x32_bf16(aq[0], b0, sacc[nt], 0, 0, 0);
    sacc[nt] = __builtin_amdgcn_mfma_f32_16x16x32_bf16(aq[1], b1, sacc[nt], 0, 0, 0);
  }
  __builtin_amdgcn_s_setprio(0);

  // softmax entirely in registers (round-2 verified)
  const float scale = 0.125f;
  float inva[4];
  for (int r = 0; r < 4; ++r) {
    float mx = -1e30f;
#pragma unroll
    for (int nt = 0; nt < 20; ++nt) {
      int n = nt * 16 + lcol;
      float s = sacc[nt][r] * scale;
      if (n < KEEP) mx = fmaxf(mx, s);
    }
    for (int off = 1; off < 16; off <<= 1) mx = fmaxf(mx, __shfl_xor(mx, off, 64));
    float sum = 0.f;
#pragma unroll
    for (int nt = 0; nt < 20; ++nt) {
      int n = nt * 16 + lcol;
      float e = (n < KEEP) ? __expf(sacc[nt][r] * scale - mx) : 0.f;
      sacc[nt][r] = e;
      sum += e;
    }
    for (int off = 1; off < 16; off <<= 1) sum += __shfl_xor(sum, off, 64);
    inva[r] = 1.f / sum;
  }

  // write P (bf16) into wave-private rows, XOR-swizzled (round-2 verified)
#pragma unroll
  for (int r = 0; r < 4; ++r) {
    int rowl = w * 16 + quad * 4 + r;
    int swp = rowl & 7;
#pragma unroll
    for (int nt = 0; nt < 20; ++nt) {
      int n = nt * 16 + lcol;
      int u = n >> 3;
      int u2 = (u & 0x38) | ((u & 7) ^ swp);
      P[rowl * 320 + u2 * 8 + (n & 7)] = f2bf(sacc[nt][r] * inva[r]);
    }
  }
  // same-wave write->read ordering only; NO barrier (rows are wave-private)
  asm volatile("s_waitcnt lgkmcnt(0)" ::: "memory");
  __builtin_amdgcn_sched_barrier(0);

  // PV: P from own wave's LDS rows (swizzled), V^T streamed from global
  floatx4 oacc[4] = {};
  const int prow = w * 16 + lcol;
  const int psw = prow & 7;
  __builtin_amdgcn_s_setprio(1);
#pragma unroll
  for (int kc = 0; kc < 10; ++kc) {
    int u = kc * 4 + quad;
    int u2 = (u & 0x38) | ((u & 7) ^ psw);
    bf16x8 pa = *(const bf16x8*)(P + prow * 320 + u2 * 8);
#pragma unroll
    for (int nt = 0; nt < 4; ++nt) {
      bf16x8 vb = *(const bf16x8*)(VpT + ((size_t)by * 64 + nt * 16 + lcol) * KP + kc * 32 + quad * 8);
      oacc[nt] = __builtin_amdgcn_mfma_f32_16x16x32_bf16(pa, vb, oacc[nt], 0, 0, 0);
    }
  }
  __builtin_amdgcn_s_setprio(0);

  int b = by / H_, h = by - b * H_;
#pragma unroll
  for (int nt = 0; nt < 4; ++nt)
#pragma unroll
    for (int r = 0; r < 4; ++r) {
      int qr = bx * 64 + w * 16 + quad * 4 + r;
      if (qr < N_TOK)
        attnout[((size_t)(b * N_TOK + qr)) * C_ + h * 64 + nt * 16 + lcol] = f2bf(oacc[nt][r]);
    }
}

// ---------------------------------------------------------------------------
// 8. Proj GEMM: 8-phase core, fp32 out + bias
__global__ __launch_bounds__(256) void proj_gemm_kernel(
    const unsigned short* __restrict__ A, const unsigned short* __restrict__ Bt,
    const float* __restrict__ bias, float* __restrict__ out) {
  __shared__ unsigned short As[2 * 8192];
  __shared__ unsigned short Bs[2 * 8192];
  const int tid = threadIdx.x;
  const int lane = tid & 63, wv = tid >> 6;
  const int quad = lane >> 4, lcol = lane & 15;
  const int wm = wv & 1, wn = wv >> 1;
  int sid = blockIdx.x;
  int m_t, n_t;
  if (sid < 1728) {
    int sb = sid / 48, r = sid % 48;
    m_t = sb * 8 + (r & 7);
    n_t = r >> 3;
  } else { m_t = 288; n_t = sid - 1728; }
  const int m0 = m_t * 128, n0 = n_t * 128;

  floatx4 acc[4][4] = {};
  gemm8_core(A, Bt, m0, n0, tid, As, Bs, acc);

  const int nbase = n0 + wn * 64;
  float bv[4];
#pragma unroll
  for (int nt = 0; nt < 4; ++nt) bv[nt] = bias[nbase + nt * 16 + lcol];
#pragma unroll
  for (int mt = 0; mt < 4; ++mt)
#pragma unroll
    for (int r = 0; r < 4; ++r) {
      int m = m0 + wm * 64 + mt * 16 + quad * 4 + r;
      if (m >= M_ROWS) continue;
#pragma unroll
      for (int nt = 0; nt < 4; ++nt)
        out[(size_t)m * C_ + nbase + nt * 16 + lcol] = acc[mt][nt][r] + bv[nt];
    }
}

// ---------------------------------------------------------------------------
extern "C" void kernel_launch(void* const* d_in, const int* in_sizes, int n_in,
                              void* d_out, int out_size, void* d_ws, size_t ws_size,
                              hipStream_t stream) {
  const float* x     = (const float*)d_in[0];
  const float* mask  = (const float*)d_in[1];
  const float* Wqkv  = (const float*)d_in[2];
  const float* bqkv  = (const float*)d_in[3];
  const float* Wproj = (const float*)d_in[4];
  const float* bproj = (const float*)d_in[5];
  float* out = (float*)d_out;

  char* ws = (char*)d_ws;
  unsigned short* xb     = (unsigned short*)(ws);                  // 56,819,712
  unsigned short* attno  = xb;                                     // reuse
  unsigned short* WqkvT  = (unsigned short*)(ws + 56819712);       //  3,538,944
  unsigned short* WprojT = (unsigned short*)(ws + 60358656);       //  1,179,648
  int*            pos    = (int*)(ws + 61538304);                  //  1,772,544
  unsigned short* Qb     = (unsigned short*)(ws + 63310848);       // 56,721,408
  unsigned short* Kpb    = (unsigned short*)(ws + 120032256);      // 31,457,280
  unsigned short* Vpb    = (unsigned short*)(ws + 151489536);      // 31,457,280
  unsigned short* VpTb   = (unsigned short*)(ws + 182946816);      // 31,457,280

  hipLaunchKernelGGL(topk_kernel,     dim3(768),      dim3(576), 0, stream, mask, pos);
  hipLaunchKernelGGL(convx_kernel,    dim3(27744),    dim3(256), 0, stream, x, xb);
  hipLaunchKernelGGL(convwT_kernel,   dim3(36, 12),   dim3(256), 0, stream, Wqkv, WqkvT, 2304);
  hipLaunchKernelGGL(convwT_kernel,   dim3(12, 12),   dim3(256), 0, stream, Wproj, WprojT, 768);
  hipLaunchKernelGGL(zeropad_kernel,  dim3(5952),     dim3(256), 0, stream, Kpb, Vpb);
  hipLaunchKernelGGL(qkv_gemm_kernel, dim3(5202),     dim3(256), 0, stream, xb, WqkvT, bqkv, pos, Qb, Kpb, Vpb);
  hipLaunchKernelGGL(transv_kernel,   dim3(5, 768),   dim3(256), 0, stream, Vpb, VpTb);
  hipLaunchKernelGGL(attn_kernel,     dim3(7680),     dim3(256), 0, stream, Qb, Kpb, VpTb, attno);
  hipLaunchKernelGGL(proj_gemm_kernel,dim3(1734),     dim3(256), 0, stream, attno, WprojT, bproj, out);
}

// Round 7
// 595.443 us; speedup vs baseline: 1.2909x; 1.2909x over previous
//
#include <hip/hip_runtime.h>
#include <stdint.h>

// Problem constants
#define B_      64
#define N_TOK   577
#define C_      768
#define H_      12
#define BH_     768      // B_*H_
#define M_ROWS  36928    // B_*N_TOK
#define M_PAD   36992    // 289 * 128
#define KEEP    289      // kept keys incl CLS
#define KP      320      // padded key count (20 * 16)

typedef __attribute__((ext_vector_type(8))) short   bf16x8;
typedef __attribute__((ext_vector_type(4))) float   floatx4;
typedef __attribute__((ext_vector_type(4))) short   short4v;

static __device__ __forceinline__ unsigned short f2bf(float f) {
  union { float f; unsigned u; } a; a.f = f;
  unsigned u = a.u;
  u = u + 0x7FFFu + ((u >> 16) & 1u);   // RNE; finite inputs
  return (unsigned short)(u >> 16);
}

static __device__ __forceinline__ void gl_lds16(const void* g, void* l) {
  __builtin_amdgcn_global_load_lds(
      (const __attribute__((address_space(1))) void*)g,
      (__attribute__((address_space(3))) void*)l, 16, 0, 0);
}

// ---------------------------------------------------------------------------
// 1. top-k(288) per (b,h) row of mask[768][576] -> pos[768][577]
__global__ void topk_kernel(const float* __restrict__ mask, int* __restrict__ pos) {
  __shared__ float vals[576];
  __shared__ int woff[9];
  int row = blockIdx.x;
  int t = threadIdx.x;
  float v = mask[(size_t)row * 576 + t];
  vals[t] = v;
  __syncthreads();
  int rank = 0;
  for (int j = 0; j < 576; ++j) {
    float u = vals[j];
    rank += ((u > v) || (u == v && j < t)) ? 1 : 0;
  }
  bool sel = rank < (KEEP - 1);
  unsigned long long ball = __ballot(sel ? 1 : 0);
  int lane = t & 63, w = t >> 6;
  int lp = __popcll(ball & ((1ull << lane) - 1ull));
  if (lane == 0) woff[w] = __popcll(ball);
  __syncthreads();
  int base = 0;
  for (int i = 0; i < w; ++i) base += woff[i];
  pos[(size_t)row * 577 + 1 + t] = sel ? (1 + base + lp) : -1;
  if (t == 0) pos[(size_t)row * 577] = 0;
}

// ---------------------------------------------------------------------------
// 2. x fp32 -> bf16, padded rows zeroed
__global__ void convx_kernel(const float* __restrict__ x, unsigned short* __restrict__ xb) {
  size_t i = ((size_t)blockIdx.x * 256 + threadIdx.x) * 4;
  short4v o;
  if (i < (size_t)M_ROWS * C_) {
    float4 v = *(const float4*)(x + i);
    o.x = (short)f2bf(v.x); o.y = (short)f2bf(v.y);
    o.z = (short)f2bf(v.z); o.w = (short)f2bf(v.w);
  } else {
    o.x = 0; o.y = 0; o.z = 0; o.w = 0;
  }
  *(short4v*)(xb + i) = o;
}

// 3. W [768][N] fp32 -> Wt [N][768] bf16, tiled 64x64 via LDS (both sides coalesced)
__global__ void convwT_kernel(const float* __restrict__ W, unsigned short* __restrict__ Wt,
                              int N) {
  __shared__ unsigned short tile[64 * 72];
  int n0 = blockIdx.x * 64, k0 = blockIdx.y * 64;
  int t = threadIdx.x;
  for (int p = 0; p < 4; ++p) {           // 64 k-rows x 16 float4 chunks
    int s = p * 256 + t;
    int k = s >> 4, nc = s & 15;
    float4 v = *(const float4*)(W + (size_t)(k0 + k) * N + n0 + nc * 4);
    short4v o;
    o.x = (short)f2bf(v.x); o.y = (short)f2bf(v.y);
    o.z = (short)f2bf(v.z); o.w = (short)f2bf(v.w);
    *(short4v*)(tile + k * 72 + nc * 4) = o;
  }
  __syncthreads();
  for (int p = 0; p < 2; ++p) {           // 64 n-rows x 8 k-chunks of 8
    int s = p * 256 + t;
    int n = s >> 3, kc = s & 7;
    bf16x8 o;
    for (int j = 0; j < 8; ++j) o[j] = (short)tile[(kc * 8 + j) * 72 + n];
    *(bf16x8*)(Wt + (size_t)(n0 + n) * 768 + k0 + kc * 8) = o;
  }
}

// 4. zero pad rows [289..320) of Kp and Vp
__global__ void zeropad_kernel(unsigned short* __restrict__ Kp, unsigned short* __restrict__ Vp) {
  size_t idx = (size_t)blockIdx.x * 256 + threadIdx.x;  // 768*31*64 exact
  int bh = (int)(idx / (31 * 64));
  int rem = (int)(idx % (31 * 64));
  int r = KEEP + rem / 64, d = rem & 63;
  size_t o = ((size_t)bh * KP + r) * 64 + d;
  Kp[o] = 0; Vp[o] = 0;
}

// ---------------------------------------------------------------------------
// 8-phase counted-vmcnt GEMM core (T3+T4+T5), 128x128 tile, BK=64, 4 waves.
// (verified in round 4)
static __device__ __forceinline__ void stage_half(const unsigned short* src,
                                                  unsigned short* lds, int tid) {
#pragma unroll
  for (int c = 0; c < 2; ++c) {
    int s = c * 256 + tid;
    int r = s >> 3, cs = s & 7;
    int gc = (cs ^ (r & 7)) << 3;
    gl_lds16(src + (size_t)r * 768 + gc, lds + s * 8);
  }
}

static __device__ __forceinline__ void gemm8_core(
    const unsigned short* __restrict__ A, const unsigned short* __restrict__ Bt,
    int m0, int n0, int tid, unsigned short* As, unsigned short* Bs,
    floatx4 (&acc)[4][4]) {
  const int lane = tid & 63, wv = tid >> 6;
  const int quad = lane >> 4, lcol = lane & 15;
  const int wm = wv & 1, wn = wv >> 1;
  const int swz = lcol & 7;

#define STG_A(kt, half) stage_half(A  + (size_t)(m0 + 64*(half)) * 768 + (kt)*64, \
                                   As + ((kt)&1)*8192 + (half)*4096, tid)
#define STG_B(kt, half) stage_half(Bt + (size_t)(n0 + 64*(half)) * 768 + (kt)*64, \
                                   Bs + ((kt)&1)*8192 + (half)*4096, tid)

  // prologue: tile0 fully, tile1 all but B-half1 (14 loads in flight/wave)
  STG_A(0, 0); STG_A(0, 1); STG_B(0, 0); STG_B(0, 1);
  STG_A(1, 0); STG_A(1, 1); STG_B(1, 0);
  asm volatile("s_waitcnt vmcnt(6)" ::: "memory");
  __builtin_amdgcn_s_barrier();

  for (int t = 0; t < 12; ++t) {
    const unsigned short* Asl = As + (t & 1) * 8192;
    const unsigned short* Bsl = Bs + (t & 1) * 8192;

    bf16x8 af[4][2], bfr[4][2];
#pragma unroll
    for (int i = 0; i < 4; ++i)
#pragma unroll
      for (int ks = 0; ks < 2; ++ks) {
        int cc = ks * 4 + quad;
        af[i][ks]  = *(const bf16x8*)(Asl + (wm * 64 + i * 16 + lcol) * 64 + ((cc ^ swz) << 3));
        bfr[i][ks] = *(const bf16x8*)(Bsl + (wn * 64 + i * 16 + lcol) * 64 + ((cc ^ swz) << 3));
      }
    if (t + 1 < 12) STG_B(t + 1, 1);
    asm volatile("s_waitcnt lgkmcnt(0)" ::: "memory");
    __builtin_amdgcn_sched_barrier(0);
    __builtin_amdgcn_s_barrier();
    __builtin_amdgcn_s_setprio(1);
#pragma unroll
    for (int j = 0; j < 4; ++j)
#pragma unroll
      for (int ks = 0; ks < 2; ++ks)
        acc[0][j] = __builtin_amdgcn_mfma_f32_16x16x32_bf16(af[0][ks], bfr[j][ks], acc[0][j], 0, 0, 0);
    __builtin_amdgcn_s_setprio(0);
    __builtin_amdgcn_s_barrier();

#pragma unroll
    for (int p = 1; p < 4; ++p) {
      if (t + 2 < 12) {
        if (p == 1)      STG_A(t + 2, 0);
        else if (p == 2) STG_A(t + 2, 1);
        else             STG_B(t + 2, 0);
      }
      __builtin_amdgcn_s_barrier();
      __builtin_amdgcn_s_setprio(1);
#pragma unroll
      for (int j = 0; j < 4; ++j)
#pragma unroll
        for (int ks = 0; ks < 2; ++ks)
          acc[p][j] = __builtin_amdgcn_mfma_f32_16x16x32_bf16(af[p][ks], bfr[j][ks], acc[p][j], 0, 0, 0);
      __builtin_amdgcn_s_setprio(0);
      if (p == 3) {
        if (t < 10)       asm volatile("s_waitcnt vmcnt(6)" ::: "memory");
        else if (t == 10) asm volatile("s_waitcnt vmcnt(0)" ::: "memory");
      }
      __builtin_amdgcn_s_barrier();
    }
  }
#undef STG_A
#undef STG_B
}

// ---------------------------------------------------------------------------
// 5. QKV GEMM: A[M_PAD][768] x WqkvT[2304][768] -> scatter Q/Kp/Vp bf16.
//    8-phase core + XCD supertile swizzle.  Kp written in XOR-swizzled
//    d-layout (16B-unit ^ (row&7)) for attn's linear global_load_lds.
__global__ __launch_bounds__(256) void qkv_gemm_kernel(
    const unsigned short* __restrict__ A, const unsigned short* __restrict__ Bt,
    const float* __restrict__ bias, const int* __restrict__ pos,
    unsigned short* __restrict__ Q, unsigned short* __restrict__ Kp,
    unsigned short* __restrict__ Vp) {
  __shared__ unsigned short As[2 * 8192];
  __shared__ unsigned short Bs[2 * 8192];
  const int tid = threadIdx.x;
  const int lane = tid & 63, wv = tid >> 6;
  const int quad = lane >> 4, lcol = lane & 15;
  const int wm = wv & 1, wn = wv >> 1;
  int sid = blockIdx.x;
  int m_t, n_t;
  if (sid < 5184) {
    int sb = sid / 48, r = sid % 48;
    int gm = sb % 36, gn = sb / 36;
    m_t = gm * 8 + (r & 7);
    n_t = gn * 6 + (r >> 3);
  } else { m_t = 288; n_t = sid - 5184; }
  const int m0 = m_t * 128, n0 = n_t * 128;

  floatx4 acc[4][4] = {};
  gemm8_core(A, Bt, m0, n0, tid, As, Bs, acc);

  // epilogue: which & h are wave-uniform (64-col span)
  const int nbase = n0 + wn * 64;
  const int which = nbase / 768;
  const int h = (nbase - which * 768) >> 6;
  float bv[4];
#pragma unroll
  for (int nt = 0; nt < 4; ++nt) bv[nt] = bias[nbase + nt * 16 + lcol];
#pragma unroll
  for (int mt = 0; mt < 4; ++mt) {
#pragma unroll
    for (int r = 0; r < 4; ++r) {
      int m = m0 + wm * 64 + mt * 16 + quad * 4 + r;
      if (m >= M_ROWS) continue;
      int b = m / 577, t = m - b * 577;
      int bh = b * 12 + h;
      if (which == 0) {
        size_t base = ((size_t)bh * 577 + t) * 64;
#pragma unroll
        for (int nt = 0; nt < 4; ++nt)
          Q[base + nt * 16 + lcol] = f2bf(acc[mt][nt][r] + bv[nt]);
      } else {
        int p = pos[(size_t)bh * 577 + t];
        if (p >= 0) {
          size_t base = ((size_t)bh * KP + p) * 64;
          if (which == 1) {
            // XOR-swizzled K layout: 16B unit index ^= (row & 7)
            int sw = p & 7;
#pragma unroll
            for (int nt = 0; nt < 4; ++nt) {
              int d = nt * 16 + lcol;
              int d2 = (d & 7) | (((d >> 3) ^ sw) << 3);
              Kp[base + d2] = f2bf(acc[mt][nt][r] + bv[nt]);
            }
          } else {
#pragma unroll
            for (int nt = 0; nt < 4; ++nt)
              Vp[base + nt * 16 + lcol] = f2bf(acc[mt][nt][r] + bv[nt]);
          }
        }
      }
    }
  }
}

// 6. Vp[bh][320][64] -> VpT[bh][64][320], tiled 64x64 via LDS.
//    Output is XOR-swizzled per d-row: 16B-unit low-3 ^= (d & 7), so attn can
//    global_load_lds it linearly and ds_read_b128 conflict-free.
__global__ void transv_kernel(const unsigned short* __restrict__ Vp,
                              unsigned short* __restrict__ VpT) {
  __shared__ unsigned short tile[64 * 72];
  int bh = blockIdx.y, p0 = blockIdx.x * 64;
  int t = threadIdx.x;
  for (int pp = 0; pp < 2; ++pp) {       // 64 p-rows x 8 d-chunks of 8
    int s = pp * 256 + t;
    int p = s >> 3, dc = s & 7;
    bf16x8 v = *(const bf16x8*)(Vp + ((size_t)bh * KP + p0 + p) * 64 + dc * 8);
    *(bf16x8*)(tile + p * 72 + dc * 8) = v;
  }
  __syncthreads();
  for (int pp = 0; pp < 2; ++pp) {       // 64 d-rows x 8 p-chunks of 8
    int s = pp * 256 + t;
    int d = s >> 3, pc = s & 7;
    bf16x8 o;
    for (int j = 0; j < 8; ++j) o[j] = (short)tile[(pc * 8 + j) * 72 + d];
    int pc2 = pc ^ (d & 7);              // swizzle within the 8-unit group
    *(bf16x8*)(VpT + ((size_t)bh * 64 + d) * KP + p0 + pc2 * 8) = o;
  }
}

// ---------------------------------------------------------------------------
// 7. Attention: round-4 verified skeleton + V^T LDS staging (T14 overlap).
//    - XCD-affine head grid; K tile + V^T tile staged via global_load_lds.
//    - vmcnt(10) after staging waits only K(+Q); V drains at 2nd barrier
//      (free: ~2000 cycles of QK^T+softmax in between).
//    - S buffer time-shared K -> P (round-4); Vs separate (80 KB total).
//    - All LDS reads XOR-swizzle conflict-free (K/P round-4; V new).
__global__ __launch_bounds__(256) void attn_kernel(
    const unsigned short* __restrict__ Q, const unsigned short* __restrict__ Kp,
    const unsigned short* __restrict__ VpT, unsigned short* __restrict__ attnout) {
  __shared__ unsigned short S[320 * 64];    // 40960 B: K (swizzled), then P[64][320]
  __shared__ unsigned short Vs[64 * 320];   // 40960 B: V^T (pre-swizzled global)
  const int tid = threadIdx.x;
  const int lane = tid & 63, w = tid >> 6;
  const int quad = lane >> 4, lcol = lane & 15;
  const int g = blockIdx.x;
  const int chunk = g / 80, within = g - chunk * 80;
  const int by = chunk * 8 + (within & 7);   // head index (bh)
  const int bx = within >> 3;                // q-tile 0..9
  const int q0 = bx * 64 + w * 16;

  // Q register loads FIRST (so vmcnt(10) below also covers them)
  bf16x8 aq[2];
  {
    int qr = q0 + lcol;
    if (qr < N_TOK) {
      const unsigned short* qp = Q + ((size_t)by * N_TOK + qr) * 64;
      aq[0] = *(const bf16x8*)(qp + quad * 8);
      aq[1] = *(const bf16x8*)(qp + 32 + quad * 8);
    } else {
      bf16x8 z = {0, 0, 0, 0, 0, 0, 0, 0};
      aq[0] = z; aq[1] = z;
    }
  }
  __builtin_amdgcn_sched_barrier(0);

  // async stage: K (10 loads), then V^T (10 loads) — order pinned
  const unsigned short* kg = Kp + (size_t)by * KP * 64;
#pragma unroll
  for (int c = 0; c < 10; ++c) {
    int s = c * 256 + tid;
    gl_lds16(kg + s * 8, S + s * 8);
  }
  __builtin_amdgcn_sched_barrier(0);
  const unsigned short* vg = VpT + (size_t)by * 64 * KP;
#pragma unroll
  for (int c = 0; c < 10; ++c) {
    int s = c * 256 + tid;
    gl_lds16(vg + s * 8, Vs + s * 8);
  }
  __builtin_amdgcn_sched_barrier(0);

  // K (+Q) resident chip-wide; V's 10 loads remain in flight
  asm volatile("s_waitcnt vmcnt(10)" ::: "memory");
  __builtin_amdgcn_sched_barrier(0);
  __builtin_amdgcn_s_barrier();

  // QK^T from LDS (swizzled K); nt=19 all-padding -> skipped
  floatx4 sacc[20] = {};
  __builtin_amdgcn_s_setprio(1);
#pragma unroll
  for (int nt = 0; nt < 19; ++nt) {
    int r16 = nt * 16 + lcol;
    const unsigned short* kb = S + r16 * 64;
    int sw = r16 & 7;
    bf16x8 b0 = *(const bf16x8*)(kb + ((quad ^ sw) << 3));
    bf16x8 b1 = *(const bf16x8*)(kb + (((quad + 4) ^ sw) << 3));
    sacc[nt] = __builtin_amdgcn_mfma_f32_16x16x32_bf16(aq[0], b0, sacc[nt], 0, 0, 0);
    sacc[nt] = __builtin_amdgcn_mfma_f32_16x16x32_bf16(aq[1], b1, sacc[nt], 0, 0, 0);
  }
  __builtin_amdgcn_s_setprio(0);

  // softmax entirely in registers (round-4 verified)
  const float scale = 0.125f;
  float inva[4];
  for (int r = 0; r < 4; ++r) {
    float mx = -1e30f;
#pragma unroll
    for (int nt = 0; nt < 20; ++nt) {
      int n = nt * 16 + lcol;
      float s = sacc[nt][r] * scale;
      if (n < KEEP) mx = fmaxf(mx, s);
    }
    for (int off = 1; off < 16; off <<= 1) mx = fmaxf(mx, __shfl_xor(mx, off, 64));
    float sum = 0.f;
#pragma unroll
    for (int nt = 0; nt < 20; ++nt) {
      int n = nt * 16 + lcol;
      float e = (n < KEEP) ? __expf(sacc[nt][r] * scale - mx) : 0.f;
      sacc[nt][r] = e;
      sum += e;
    }
    for (int off = 1; off < 16; off <<= 1) sum += __shfl_xor(sum, off, 64);
    inva[r] = 1.f / sum;
  }

  // all waves' K ds_reads drained + own V stage drained, then barrier:
  // S is free for P overwrite, and Vs is resident block-wide.
  asm volatile("s_waitcnt lgkmcnt(0) vmcnt(0)" ::: "memory");
  __builtin_amdgcn_sched_barrier(0);
  __builtin_amdgcn_s_barrier();

  // write P (bf16) into S, XOR-swizzled: 16B-unit low3 ^= (row & 7)
#pragma unroll
  for (int r = 0; r < 4; ++r) {
    int rowl = w * 16 + quad * 4 + r;
    int swp = rowl & 7;
#pragma unroll
    for (int nt = 0; nt < 20; ++nt) {
      int n = nt * 16 + lcol;
      int u = n >> 3;
      int u2 = (u & 0x38) | ((u & 7) ^ swp);
      S[rowl * 320 + u2 * 8 + (n & 7)] = f2bf(sacc[nt][r] * inva[r]);
    }
  }
  // P rows are wave-private: own write->read ordering only, no barrier
  asm volatile("s_waitcnt lgkmcnt(0)" ::: "memory");
  __builtin_amdgcn_sched_barrier(0);

  // PV: P and V^T both from LDS (swizzled), no global traffic
  floatx4 oacc[4] = {};
  const int prow = w * 16 + lcol;
  const int psw = prow & 7;
  const int vsw = lcol & 7;                // (nt*16+lcol)&7 == lcol&7
  __builtin_amdgcn_s_setprio(1);
#pragma unroll
  for (int kc = 0; kc < 10; ++kc) {
    int u = kc * 4 + quad;
    int pu2 = (u & 0x38) | ((u & 7) ^ psw);
    bf16x8 pa = *(const bf16x8*)(S + prow * 320 + pu2 * 8);
    int vu2 = (u & 0x38) | ((u & 7) ^ vsw);
#pragma unroll
    for (int nt = 0; nt < 4; ++nt) {
      bf16x8 vb = *(const bf16x8*)(Vs + (nt * 16 + lcol) * 320 + vu2 * 8);
      oacc[nt] = __builtin_amdgcn_mfma_f32_16x16x32_bf16(pa, vb, oacc[nt], 0, 0, 0);
    }
  }
  __builtin_amdgcn_s_setprio(0);

  int b = by / H_, h = by - b * H_;
#pragma unroll
  for (int nt = 0; nt < 4; ++nt)
#pragma unroll
    for (int r = 0; r < 4; ++r) {
      int qr = bx * 64 + w * 16 + quad * 4 + r;
      if (qr < N_TOK)
        attnout[((size_t)(b * N_TOK + qr)) * C_ + h * 64 + nt * 16 + lcol] = f2bf(oacc[nt][r]);
    }
}

// ---------------------------------------------------------------------------
// 8. Proj GEMM: 8-phase core, fp32 out + bias
__global__ __launch_bounds__(256) void proj_gemm_kernel(
    const unsigned short* __restrict__ A, const unsigned short* __restrict__ Bt,
    const float* __restrict__ bias, float* __restrict__ out) {
  __shared__ unsigned short As[2 * 8192];
  __shared__ unsigned short Bs[2 * 8192];
  const int tid = threadIdx.x;
  const int lane = tid & 63, wv = tid >> 6;
  const int quad = lane >> 4, lcol = lane & 15;
  const int wm = wv & 1, wn = wv >> 1;
  int sid = blockIdx.x;
  int m_t, n_t;
  if (sid < 1728) {
    int sb = sid / 48, r = sid % 48;
    m_t = sb * 8 + (r & 7);
    n_t = r >> 3;
  } else { m_t = 288; n_t = sid - 1728; }
  const int m0 = m_t * 128, n0 = n_t * 128;

  floatx4 acc[4][4] = {};
  gemm8_core(A, Bt, m0, n0, tid, As, Bs, acc);

  const int nbase = n0 + wn * 64;
  float bv[4];
#pragma unroll
  for (int nt = 0; nt < 4; ++nt) bv[nt] = bias[nbase + nt * 16 + lcol];
#pragma unroll
  for (int mt = 0; mt < 4; ++mt)
#pragma unroll
    for (int r = 0; r < 4; ++r) {
      int m = m0 + wm * 64 + mt * 16 + quad * 4 + r;
      if (m >= M_ROWS) continue;
#pragma unroll
      for (int nt = 0; nt < 4; ++nt)
        out[(size_t)m * C_ + nbase + nt * 16 + lcol] = acc[mt][nt][r] + bv[nt];
    }
}

// ---------------------------------------------------------------------------
extern "C" void kernel_launch(void* const* d_in, const int* in_sizes, int n_in,
                              void* d_out, int out_size, void* d_ws, size_t ws_size,
                              hipStream_t stream) {
  const float* x     = (const float*)d_in[0];
  const float* mask  = (const float*)d_in[1];
  const float* Wqkv  = (const float*)d_in[2];
  const float* bqkv  = (const float*)d_in[3];
  const float* Wproj = (const float*)d_in[4];
  const float* bproj = (const float*)d_in[5];
  float* out = (float*)d_out;

  char* ws = (char*)d_ws;
  unsigned short* xb     = (unsigned short*)(ws);                  // 56,819,712
  unsigned short* attno  = xb;                                     // reuse
  unsigned short* WqkvT  = (unsigned short*)(ws + 56819712);       //  3,538,944
  unsigned short* WprojT = (unsigned short*)(ws + 60358656);       //  1,179,648
  int*            pos    = (int*)(ws + 61538304);                  //  1,772,544
  unsigned short* Qb     = (unsigned short*)(ws + 63310848);       // 56,721,408
  unsigned short* Kpb    = (unsigned short*)(ws + 120032256);      // 31,457,280
  unsigned short* Vpb    = (unsigned short*)(ws + 151489536);      // 31,457,280
  unsigned short* VpTb   = (unsigned short*)(ws + 182946816);      // 31,457,280

  hipLaunchKernelGGL(topk_kernel,     dim3(768),      dim3(576), 0, stream, mask, pos);
  hipLaunchKernelGGL(convx_kernel,    dim3(27744),    dim3(256), 0, stream, x, xb);
  hipLaunchKernelGGL(convwT_kernel,   dim3(36, 12),   dim3(256), 0, stream, Wqkv, WqkvT, 2304);
  hipLaunchKernelGGL(convwT_kernel,   dim3(12, 12),   dim3(256), 0, stream, Wproj, WprojT, 768);
  hipLaunchKernelGGL(zeropad_kernel,  dim3(5952),     dim3(256), 0, stream, Kpb, Vpb);
  hipLaunchKernelGGL(qkv_gemm_kernel, dim3(5202),     dim3(256), 0, stream, xb, WqkvT, bqkv, pos, Qb, Kpb, Vpb);
  hipLaunchKernelGGL(transv_kernel,   dim3(5, 768),   dim3(256), 0, stream, Vpb, VpTb);
  hipLaunchKernelGGL(attn_kernel,     dim3(7680),     dim3(256), 0, stream, Qb, Kpb, VpTb, attno);
  hipLaunchKernelGGL(proj_gemm_kernel,dim3(1734),     dim3(256), 0, stream, attno, WprojT, bproj, out);
}